// Round 10
// baseline (172.702 us; speedup 1.0000x reference)
//
#include <hip/hip_runtime.h>
#include <hip/hip_bf16.h>

#define IN_DIM 128
#define HID_DIM 64
#define OUT_DIM 16

// Stripe/bin geometry: 128 nodes per stripe
#define SSHIFT 7
#define SMASK 127
// Edge chunking: 245 blocks -> all CUs busy
#define CHUNK 4096
#define CBLK 256
// Per-stripe bucket slack (mean 2560, sigma ~51 -> 4096 is ~30 sigma)
#define SLACK_SHIFT 12

// bf16 helpers: round-to-nearest-even pack, bit-shift unpack
static __device__ __forceinline__ unsigned short f2bf(float f) {
    unsigned u = __float_as_uint(f);
    unsigned r = u + 0x7fffu + ((u >> 16) & 1u);
    return (unsigned short)(r >> 16);
}
static __device__ __forceinline__ unsigned packbf2(float a, float b) {
    return (unsigned)f2bf(a) | ((unsigned)f2bf(b) << 16);
}
static __device__ __forceinline__ float bflo(unsigned v) { return __uint_as_float(v << 16); }
static __device__ __forceinline__ float bfhi(unsigned v) { return __uint_as_float(v & 0xffff0000u); }

// ---------------------------------------------------------------------------
// passAC (merged passA+passB1+passC): per-block LDS histogram, ONE global
// atomic per (block,stripe) reserves a range in stripe bucket s*4096, then
// scatter packed (dl<<17)|src into eb. gcur must be zeroed beforehand; after
// this kernel gcur[s] = stripe total.
// ---------------------------------------------------------------------------
__global__ __launch_bounds__(CBLK) void passAC(const int* __restrict__ src,
                                               const int* __restrict__ dst,
                                               int* __restrict__ gcur,
                                               int* __restrict__ eb,
                                               int E, int NS) {
    __shared__ int cnt[512];
    __shared__ int cur[512];
    int t = threadIdx.x, b = blockIdx.x;
    for (int s = t; s < NS; s += CBLK) cnt[s] = 0;
    __syncthreads();
    int base = b * CHUNK;
    #pragma unroll 4
    for (int k = 0; k < CHUNK; k += CBLK) {
        int i = base + k + t;
        if (i < E) atomicAdd(&cnt[dst[i] >> SSHIFT], 1);
    }
    __syncthreads();
    for (int s = t; s < NS; s += CBLK) {
        int c = cnt[s];
        int o = (c > 0) ? atomicAdd(&gcur[s], c) : 0;
        cur[s] = (s << SLACK_SHIFT) + o;
    }
    __syncthreads();
    #pragma unroll 4
    for (int k = 0; k < CHUNK; k += CBLK) {
        int i = base + k + t;
        if (i < E) {
            int d = dst[i];
            int s = d >> SSHIFT;
            int pos = atomicAdd(&cur[s], 1);
            eb[pos] = src[i] | ((d & SMASK) << 17);
        }
    }
}

// ---------------------------------------------------------------------------
// passD: per-stripe LDS counting sort from bucket s*4096 -> packed CSR +
// row_ptr + dinv. b0 (packed output base) = sum gcur[0..s) by block reduce.
// ---------------------------------------------------------------------------
__global__ __launch_bounds__(256) void passD(const int* __restrict__ eb,
                                             const int* __restrict__ gcur,
                                             int* __restrict__ csr_src,
                                             int* __restrict__ row_ptr,
                                             float* __restrict__ dinv,
                                             int N, int E, int NS) {
    __shared__ int red[256];
    __shared__ int deg[128], incl[128], cur[128];
    int s = blockIdx.x, t = threadIdx.x;
    if (t < 128) deg[t] = 0;
    int part = 0;
    for (int k = t; k < s; k += 256) part += gcur[k];
    red[t] = part;
    __syncthreads();
    for (int off = 128; off >= 1; off >>= 1) {
        if (t < off) red[t] += red[t + off];
        __syncthreads();
    }
    int b0 = red[0];                     // packed csr base for this stripe
    int cnt = gcur[s];                   // stripe total
    int ebase = s << SLACK_SHIFT;        // bucket base in eb
    for (int k = t; k < cnt; k += 256) atomicAdd(&deg[eb[ebase + k] >> 17], 1);
    __syncthreads();
    if (t < 128) incl[t] = deg[t];
    __syncthreads();
    for (int off = 1; off < 128; off <<= 1) {
        int tmp = 0;
        if (t < 128 && t >= off) tmp = incl[t - off];
        __syncthreads();
        if (t < 128) incl[t] += tmp;
        __syncthreads();
    }
    if (t < 128) {
        int loff = incl[t] - deg[t];
        cur[t] = b0 + loff;
        int n = (s << SSHIFT) + t;
        if (n < N) {
            row_ptr[n] = b0 + loff;
            dinv[n] = rsqrtf((float)(deg[t] + 1));
        }
    }
    if (s == NS - 1 && t == 0) row_ptr[N] = E;
    __syncthreads();
    for (int k = t; k < cnt; k += 256) {
        int v = eb[ebase + k];
        int dl = v >> 17;
        int p = atomicAdd(&cur[dl], 1);
        csr_src[p] = v & 0x1FFFF;
    }
}

// ---------------------------------------------------------------------------
// GEMM1 (v2): 32 nodes/block. h1 = bf16( (x @ W1) * dinv[n] ), row = 8 uint4.
// sx padded to stride 129 (129%32==1) -> xr[k] reads hit 8 distinct banks
// across ln (was 8-way conflict at stride 128). W1 staging amortized over
// 2x nodes vs v1. Row N = zeros (dummy, via dn=0).
// ---------------------------------------------------------------------------
__global__ __launch_bounds__(256) void gemm1_kernel(const float* __restrict__ x,
                                                    const float* __restrict__ W1,
                                                    const float* __restrict__ dinv,
                                                    unsigned* __restrict__ h1u, int N) {
    __shared__ __align__(16) float sW[IN_DIM * HID_DIM];   // 32 KB
    __shared__ __align__(16) float sx[32 * 129];           // 16.1 KB, padded
    int t = threadIdx.x;
    int node0 = blockIdx.x * 32;

    const float4* W4  = (const float4*)W1;
    float4*       sW4 = (float4*)sW;
    #pragma unroll
    for (int i = t; i < (IN_DIM * HID_DIM) / 4; i += 256) sW4[i] = W4[i];

    const float4* x4 = (const float4*)x;
    #pragma unroll
    for (int i = t; i < 1024; i += 256) {       // 32 rows x 32 float4
        int r = i >> 5, c = i & 31;
        int n = node0 + r; if (n >= N) n = 0;   // clamp; dummy row gets dn=0
        float4 v = x4[(size_t)n * 32 + c];
        float* p = sx + r * 129 + 4 * c;
        p[0] = v.x; p[1] = v.y; p[2] = v.z; p[3] = v.w;
    }
    __syncthreads();

    int ln = t >> 3, jj = t & 7;                // node 0..31, col group of 8
    int n = node0 + ln;
    float4 acc0 = {0.f, 0.f, 0.f, 0.f}, acc1 = {0.f, 0.f, 0.f, 0.f};
    const float* xr = sx + ln * 129;
    #pragma unroll 4
    for (int k = 0; k < IN_DIM; ++k) {
        float  xk = xr[k];
        const float4* wr = (const float4*)(sW + k * HID_DIM);
        float4 w0 = wr[2 * jj];
        float4 w1 = wr[2 * jj + 1];
        acc0.x += xk * w0.x; acc0.y += xk * w0.y; acc0.z += xk * w0.z; acc0.w += xk * w0.w;
        acc1.x += xk * w1.x; acc1.y += xk * w1.y; acc1.z += xk * w1.z; acc1.w += xk * w1.w;
    }
    if (n <= N) {
        float dn = (n < N) ? dinv[n] : 0.f;     // row N -> zeros
        uint4 pv;
        pv.x = packbf2(acc0.x * dn, acc0.y * dn);
        pv.y = packbf2(acc0.z * dn, acc0.w * dn);
        pv.z = packbf2(acc1.x * dn, acc1.y * dn);
        pv.w = packbf2(acc1.z * dn, acc1.w * dn);
        ((uint4*)h1u)[(size_t)n * 8 + jj] = pv;
    }
}

// ---------------------------------------------------------------------------
// Aggregation layer 1 (v4, round-9 proven): TWO nodes per wave. lane =
// (h 1b, es 0..3, dg 0..7). uint4/lane -> one dwordx4 fetches 8 edge rows
// (4/node); all wave instructions amortized over 2 nodes.
// out = relu( dinv[n]*(h1[n] + sum h1[src]) + b1 ), bf16.
// ---------------------------------------------------------------------------
__global__ __launch_bounds__(256) void agg1_kernel(const unsigned* __restrict__ h1u,
                                                   const int* __restrict__ row_ptr,
                                                   const int* __restrict__ csr_src,
                                                   const float* __restrict__ dinv,
                                                   const float* __restrict__ b1,
                                                   unsigned* __restrict__ h1au, int N) {
    int t = threadIdx.x;
    int lane = t & 63;
    int h  = lane >> 5;            // node half 0/1
    int l  = lane & 31;
    int es = l >> 3;               // edge slot 0..3
    int dg = l & 7;                // dim group: uint4 = dims 8dg..8dg+7
    int n = blockIdx.x * 8 + ((t >> 6) << 1) + h;   // 2 nodes/wave, 8/block
    if (n >= N) return;

    int e0 = row_ptr[n], e1 = row_ptr[n + 1];
    const uint4* rb = (const uint4*)h1u;     // row = 8 uint4
    int sb = h << 5;                          // shfl base for this half

    float a0 = 0.f, a1 = 0.f, a2 = 0.f, a3 = 0.f,
          a4 = 0.f, a5 = 0.f, a6 = 0.f, a7 = 0.f;

    for (int base = e0 - 1; base < e1; base += 32) {
        int idx = base + l;
        int sld = N;
        if (idx == e0 - 1) sld = n;              // self loop item
        else if (idx < e1) sld = csr_src[idx];   // predicated coalesced load
        int lim = e1 - base;
        if (lim > 32) lim = 32;
        int nr = (lim + 3) >> 2;                 // rounds of 4
        nr = (nr + 1) & ~1;                      // even # rounds (extras hit row N)
        for (int r = 0; r < nr; r += 2) {
            int sA = __shfl(sld, sb + ((r + 0) << 2) + es);
            int sB = __shfl(sld, sb + ((r + 1) << 2) + es);
            uint4 vA = rb[(size_t)sA * 8 + dg];
            uint4 vB = rb[(size_t)sB * 8 + dg];
            a0 += bflo(vA.x) + bflo(vB.x);
            a1 += bfhi(vA.x) + bfhi(vB.x);
            a2 += bflo(vA.y) + bflo(vB.y);
            a3 += bfhi(vA.y) + bfhi(vB.y);
            a4 += bflo(vA.z) + bflo(vB.z);
            a5 += bfhi(vA.z) + bfhi(vB.z);
            a6 += bflo(vA.w) + bflo(vB.w);
            a7 += bfhi(vA.w) + bfhi(vB.w);
        }
    }
    #pragma unroll
    for (int m = 8; m <= 16; m <<= 1) {
        a0 += __shfl_xor(a0, m); a1 += __shfl_xor(a1, m);
        a2 += __shfl_xor(a2, m); a3 += __shfl_xor(a3, m);
        a4 += __shfl_xor(a4, m); a5 += __shfl_xor(a5, m);
        a6 += __shfl_xor(a6, m); a7 += __shfl_xor(a7, m);
    }
    if (es == 0) {
        float dn = dinv[n];
        float4 bA = ((const float4*)b1)[2 * dg];
        float4 bB = ((const float4*)b1)[2 * dg + 1];
        float r0 = fmaxf(fmaf(dn, a0, bA.x), 0.f);
        float r1 = fmaxf(fmaf(dn, a1, bA.y), 0.f);
        float r2 = fmaxf(fmaf(dn, a2, bA.z), 0.f);
        float r3 = fmaxf(fmaf(dn, a3, bA.w), 0.f);
        float r4 = fmaxf(fmaf(dn, a4, bB.x), 0.f);
        float r5 = fmaxf(fmaf(dn, a5, bB.y), 0.f);
        float r6 = fmaxf(fmaf(dn, a6, bB.z), 0.f);
        float r7 = fmaxf(fmaf(dn, a7, bB.w), 0.f);
        uint4 pv;
        pv.x = packbf2(r0, r1); pv.y = packbf2(r2, r3);
        pv.z = packbf2(r4, r5); pv.w = packbf2(r6, r7);
        ((uint4*)h1au)[(size_t)n * 8 + dg] = pv;
    }
}

// ---------------------------------------------------------------------------
// GEMM2: h2 = bf16( (h1a @ W2) * dinv[n] ), row = 8 uints. Row N = zeros.
// ---------------------------------------------------------------------------
__global__ __launch_bounds__(256) void gemm2_kernel(const unsigned* __restrict__ h1au,
                                                    const float* __restrict__ W2,
                                                    const float* __restrict__ dinv,
                                                    unsigned* __restrict__ h2u, int N) {
    __shared__ __align__(16) float sW[HID_DIM * OUT_DIM];  // 4 KB
    __shared__ __align__(16) float sx[16 * HID_DIM];       // 4 KB
    int t = threadIdx.x;
    int node0 = blockIdx.x * 16;

    ((float4*)sW)[t] = ((const float4*)W2)[t];
    for (int i = t; i < 512; i += 256) {           // 16 rows x 32 uints
        int r = i >> 5, c = i & 31;
        int n = node0 + r; if (n >= N) n = 0;      // clamp; dummy handled by dn=0
        unsigned v = h1au[(size_t)n * 32 + c];
        float2 f; f.x = bflo(v); f.y = bfhi(v);
        *(float2*)(sx + r * HID_DIM + 2 * c) = f;
    }
    __syncthreads();

    int ln = t >> 4, j = t & 15;
    float acc = 0.f;
    const float* xr = sx + ln * HID_DIM;
    #pragma unroll 8
    for (int k = 0; k < HID_DIM; ++k) acc += xr[k] * sW[k * OUT_DIM + j];
    int n = node0 + ln;
    float other = __shfl_xor(acc, 1);              // pair dims (j even, j odd)
    if (n <= N && (j & 1) == 0) {
        float dn = (n < N) ? dinv[n] : 0.f;        // row N -> zeros (agg2 zero-pad)
        h2u[(size_t)n * 8 + (j >> 1)] = packbf2(acc * dn, other * dn);
    }
}

// ---------------------------------------------------------------------------
// Aggregation layer 2 (v4, round-9 proven): FOUR nodes per wave. lane =
// (h 2b, es 0..3, dg 0..3). uint2/lane; one load = 16 edge rows (4/node).
// h2u (1.6 MB) L2-resident. out = dinv[n]*sum + b2, fp32.
// ---------------------------------------------------------------------------
__global__ __launch_bounds__(256) void agg2_kernel(const unsigned* __restrict__ h2u,
                                                   const int* __restrict__ row_ptr,
                                                   const int* __restrict__ csr_src,
                                                   const float* __restrict__ dinv,
                                                   const float* __restrict__ b2,
                                                   float* __restrict__ out, int N) {
    int t = threadIdx.x;
    int lane = t & 63;
    int h  = lane >> 4;            // node quarter 0..3
    int l  = lane & 15;
    int es = l >> 2;               // edge slot 0..3
    int dg = l & 3;                // dim group: uint2 = dims 4dg..4dg+3
    int n = blockIdx.x * 16 + ((t >> 6) << 2) + h; // 4 nodes/wave, 16/block
    if (n >= N) return;

    int e0 = row_ptr[n], e1 = row_ptr[n + 1];
    const uint2* rb = (const uint2*)h2u;     // row = 4 uint2
    int sb = h << 4;                          // shfl base for this quarter

    float a0 = 0.f, a1 = 0.f, a2 = 0.f, a3 = 0.f;

    for (int base = e0 - 1; base < e1; base += 16) {
        int idx = base + l;
        int sld = N;
        if (idx == e0 - 1) sld = n;
        else if (idx < e1) sld = csr_src[idx];
        int lim = e1 - base;
        if (lim > 16) lim = 16;
        int nr = (lim + 3) >> 2;                 // rounds of 4
        nr = (nr + 1) & ~1;                      // even (extras hit row N)
        for (int r = 0; r < nr; r += 2) {
            int sA = __shfl(sld, sb + ((r + 0) << 2) + es);
            int sB = __shfl(sld, sb + ((r + 1) << 2) + es);
            uint2 vA = rb[(size_t)sA * 4 + dg];
            uint2 vB = rb[(size_t)sB * 4 + dg];
            a0 += bflo(vA.x) + bflo(vB.x);
            a1 += bfhi(vA.x) + bfhi(vB.x);
            a2 += bflo(vA.y) + bflo(vB.y);
            a3 += bfhi(vA.y) + bfhi(vB.y);
        }
    }
    #pragma unroll
    for (int m = 4; m <= 8; m <<= 1) {
        a0 += __shfl_xor(a0, m); a1 += __shfl_xor(a1, m);
        a2 += __shfl_xor(a2, m); a3 += __shfl_xor(a3, m);
    }
    if (es == 0) {
        float dn = dinv[n];
        float4 bb = ((const float4*)b2)[dg];
        float4 r;
        r.x = fmaf(dn, a0, bb.x);
        r.y = fmaf(dn, a1, bb.y);
        r.z = fmaf(dn, a2, bb.z);
        r.w = fmaf(dn, a3, bb.w);
        ((float4*)out)[(size_t)n * 4 + dg] = r;
    }
}

// ---------------------------------------------------------------------------
// Launch
// ---------------------------------------------------------------------------
extern "C" void kernel_launch(void* const* d_in, const int* in_sizes, int n_in,
                              void* d_out, int out_size, void* d_ws, size_t ws_size,
                              hipStream_t stream) {
    const float* x  = (const float*)d_in[0];
    const int*   ei = (const int*)d_in[1];
    const float* W1 = (const float*)d_in[2];
    const float* b1 = (const float*)d_in[3];
    const float* W2 = (const float*)d_in[4];
    const float* b2 = (const float*)d_in[5];
    float* out = (float*)d_out;

    const int N = in_sizes[0] / IN_DIM;   // 50000
    const int E = in_sizes[1] / 2;        // 1000000
    const int* src = ei;
    const int* dst = ei + E;

    const int NS = (N + SMASK) >> SSHIFT;        // 391 stripes (<= 512)
    const int BC = (E + CHUNK - 1) / CHUNK;      // 245 chunks

    char* w = (char*)d_ws;
    auto alloc = [&](size_t bytes) -> void* {
        void* p = (void*)w;
        w += (bytes + 255) & ~(size_t)255;
        return p;
    };
    int*      gcur    = (int*)     alloc((size_t)NS * 4);
    int*      eb      = (int*)     alloc((size_t)NS << SLACK_SHIFT << 2);  // bucketed
    int*      csr_src = (int*)     alloc((size_t)E * 4);
    int*      row_ptr = (int*)     alloc((size_t)(N + 1) * 4);
    float*    dinv    = (float*)   alloc((size_t)N * 4);
    unsigned* h1u     = (unsigned*)alloc((size_t)(N + 1) * 32 * 4);  // bf16 [N+1][64]
    unsigned* h1au    = (unsigned*)alloc((size_t)(N + 1) * 32 * 4);
    unsigned* h2u     = (unsigned*)alloc((size_t)(N + 1) * 8 * 4);   // bf16 [N+1][16]

    const int GB1 = (N + 32) / 32;   // gemm1: 32 nodes/block, covers row N
    const int GB2 = (N + 16) / 16;   // gemm2: 16 nodes/block, covers row N
    const int AB1 = (N + 7) / 8;     // agg1: 8 nodes/block (2 per wave)
    const int AB2 = (N + 15) / 16;   // agg2: 16 nodes/block (4 per wave)

    hipMemsetAsync(gcur, 0, (size_t)NS * 4, stream);
    passAC<<<BC, CBLK, 0, stream>>>(src, dst, gcur, eb, E, NS);
    passD <<<NS, 256,  0, stream>>>(eb, gcur, csr_src, row_ptr, dinv, N, E, NS);

    gemm1_kernel<<<GB1, 256, 0, stream>>>(x, W1, dinv, h1u, N);
    agg1_kernel <<<AB1, 256, 0, stream>>>(h1u, row_ptr, csr_src, dinv, b1, h1au, N);
    gemm2_kernel<<<GB2, 256, 0, stream>>>(h1au, W2, dinv, h2u, N);
    agg2_kernel <<<AB2, 256, 0, stream>>>(h2u, row_ptr, csr_src, dinv, b2, out, N);
}